// Round 1
// baseline (109.048 us; speedup 1.0000x reference)
//
#include <hip/hip_runtime.h>

// Problem constants (from setup_inputs): B=64, H=W=384, P=1000.
#define BB 64
#define HH 384
#define WW 384
#define PP 1000
#define NITEMS (BB * PP)          // 64000 items, one per (b, p)
#define NTERMS (NITEMS * 8)
#define NBLOCKS1 250              // 64000 / 256, exact

// 3 consecutive floats, 4-byte aligned (row of the 3x3 stencil).
struct __attribute__((aligned(4))) F3 { float a, b, c; };

// Cross-block reduction state. g_count is zero-initialized at module load
// and self-resets at the end of every grid execution, so it is correct
// across graph replays without any host-side init (and without touching
// the harness workspace at all).
__device__ float g_part[NBLOCKS1];
__device__ int   g_count = 0;

__global__ __launch_bounds__(256)
void rd_fused(const float* __restrict__ pred,
              const float* __restrict__ gt,
              const int*   __restrict__ px,
              const int*   __restrict__ py,
              float* __restrict__ out) {
    const int idx = blockIdx.x * 256 + threadIdx.x;   // [0, 64000), exact grid
    const int b = idx / PP;
    const int p = idx - b * PP;
    const int x = px[p];
    const int y = py[p];

    const float* pb = pred + (size_t)b * (HH * WW);
    const float* gb = gt   + (size_t)b * (HH * WW);
    const int c = y * WW + x;

    // 3x3 stencil as three 3-wide row loads per tensor (6 scattered instrs
    // instead of 18 scalar ones). x in [30,350) so c-WW-1 .. c+WW+1 in bounds.
    const F3 pt = *(const F3*)(pb + c - WW - 1);
    const F3 pm = *(const F3*)(pb + c      - 1);
    const F3 pbo= *(const F3*)(pb + c + WW - 1);
    const F3 gt_= *(const F3*)(gb + c - WW - 1);
    const F3 gm = *(const F3*)(gb + c      - 1);
    const F3 gbo= *(const F3*)(gb + c + WW - 1);

    const float pc = pm.b, gc = gm.b;
    // neighbor order (matches _DY/_DX; sum is order-invariant anyway):
    const float pn[8] = { pt.b, pbo.b, pm.a, pm.c, pt.a, pt.c, pbo.a, pbo.c };
    const float gn[8] = { gt_.b, gbo.b, gm.a, gm.c, gt_.a, gt_.c, gbo.a, gbo.c };

    float vp[8], vg[8], sp = 0.0f, sg = 0.0f;
    #pragma unroll
    for (int i = 0; i < 8; ++i) {
        vp[i] = pc - pn[i];
        vg[i] = gc - gn[i];
        sp += vp[i] * vp[i];
        sg += vg[i] * vg[i];
    }
    const float ip = (sp == 0.0f) ? 1.0f : rsqrtf(sp);  // ref: norm==0 -> 1
    const float ig = (sg == 0.0f) ? 1.0f : rsqrtf(sg);

    float partial = 0.0f;
    #pragma unroll
    for (int i = 0; i < 8; ++i)
        partial += fabsf(vp[i] * ip - vg[i] * ig);

    // wave-64 reduction
    #pragma unroll
    for (int o = 32; o > 0; o >>= 1)
        partial += __shfl_down(partial, o, 64);

    __shared__ float wsum[4];
    __shared__ int   slast;
    const int lane = threadIdx.x & 63;
    const int wid  = threadIdx.x >> 6;
    if (lane == 0) wsum[wid] = partial;
    __syncthreads();

    if (threadIdx.x == 0) {
        const float bsum = wsum[0] + wsum[1] + wsum[2] + wsum[3];
        // Publish block partial (plain store), release-fence, then count.
        __hip_atomic_store(&g_part[blockIdx.x], bsum,
                           __ATOMIC_RELAXED, __HIP_MEMORY_SCOPE_AGENT);
        __threadfence();  // device-scope release before the counter bump
        const int old = atomicAdd(&g_count, 1);   // device-scope by default
        slast = (old == NBLOCKS1 - 1) ? 1 : 0;
    }
    __syncthreads();

    if (slast) {
        // Last block to finish: all prior blocks' partials are visible
        // (their fence happened-before their counter increment, which
        // happened-before our observation of old == NBLOCKS1-1).
        __threadfence();  // acquire side
        const int t = threadIdx.x;
        float v = 0.0f;
        if (t < NBLOCKS1)
            v = __hip_atomic_load(&g_part[t],
                                  __ATOMIC_RELAXED, __HIP_MEMORY_SCOPE_AGENT);
        // Same shuffle tree as the old rd_stage2 -> bitwise-identical result.
        #pragma unroll
        for (int o = 32; o > 0; o >>= 1)
            v += __shfl_down(v, o, 64);

        __shared__ float w2[4];
        if (lane == 0) w2[wid] = v;
        __syncthreads();
        if (t == 0) {
            out[0] = (w2[0] + w2[1] + w2[2] + w2[3]) * (1.0f / (float)NTERMS);
            // Self-reset for the next graph replay. Agent-scope atomic store
            // so it lands in L2 (where the atomics operate) before kernel end.
            __hip_atomic_store(&g_count, 0,
                               __ATOMIC_RELAXED, __HIP_MEMORY_SCOPE_AGENT);
        }
    }
}

extern "C" void kernel_launch(void* const* d_in, const int* in_sizes, int n_in,
                              void* d_out, int out_size, void* d_ws, size_t ws_size,
                              hipStream_t stream) {
    const float* pred = (const float*)d_in[0];
    const float* gt   = (const float*)d_in[1];
    const int*   px   = (const int*)d_in[2];
    const int*   py   = (const int*)d_in[3];
    float* out = (float*)d_out;
    (void)d_ws; (void)ws_size;   // workspace intentionally unused

    rd_fused<<<NBLOCKS1, 256, 0, stream>>>(pred, gt, px, py, out);
}

// Round 2
// 101.939 us; speedup vs baseline: 1.0697x; 1.0697x over previous
//
#include <hip/hip_runtime.h>

// Problem constants (from setup_inputs): B=64, H=W=384, P=1000.
#define BB 64
#define HH 384
#define WW 384
#define PP 1000
#define NITEMS (BB * PP)          // 64000 items, one per (b, p)
#define NTERMS (NITEMS * 8)
#define NBLOCKS1 250              // 64000 / 256, exact

// 3 consecutive floats, 4-byte aligned (row of the 3x3 stencil).
struct __attribute__((aligned(4))) F3 { float a, b, c; };

// Single packed accumulator: bits [0,52) = total block-sum in 2^31 fixed
// point (max total sum < 2^20, so fx < 2^51); bits [52,62) = arrival
// counter. One atomicAdd carries BOTH the data and the election -> no
// fences, no L2 writeback/invalidate (which is what regressed round 1 on
// this 8-XCD non-coherent-L2 chip). Same-address RMWs are totally ordered
// and return the current value, so the block that observes counter==250
// already holds the complete sum. Integer adds are associative ->
// deterministic result across replays.
// Zero-initialized at module load; the electing block resets it, and its
// reset is ordered after all 250 adds in the modification order of the
// atomic location, so graph replays start clean.
__device__ unsigned long long g_acc = 0ULL;

#define CNT_ONE (1ULL << 52)
#define SUM_MASK (CNT_ONE - 1ULL)
#define FX_SCALE 2147483648.0     // 2^31

__global__ __launch_bounds__(256)
void rd_fused(const float* __restrict__ pred,
              const float* __restrict__ gt,
              const int*   __restrict__ px,
              const int*   __restrict__ py,
              float* __restrict__ out) {
    const int idx = blockIdx.x * 256 + threadIdx.x;   // [0, 64000), exact grid
    const int b = idx / PP;
    const int p = idx - b * PP;
    const int x = px[p];
    const int y = py[p];

    const float* pb = pred + (size_t)b * (HH * WW);
    const float* gb = gt   + (size_t)b * (HH * WW);
    const int c = y * WW + x;

    // 3x3 stencil as three 3-wide row loads per tensor (6 scattered instrs
    // instead of 18 scalar ones). x in [30,350) so c-WW-1 .. c+WW+1 in bounds.
    const F3 pt = *(const F3*)(pb + c - WW - 1);
    const F3 pm = *(const F3*)(pb + c      - 1);
    const F3 pbo= *(const F3*)(pb + c + WW - 1);
    const F3 gt_= *(const F3*)(gb + c - WW - 1);
    const F3 gm = *(const F3*)(gb + c      - 1);
    const F3 gbo= *(const F3*)(gb + c + WW - 1);

    const float pc = pm.b, gc = gm.b;
    // neighbor order (matches _DY/_DX; sum is order-invariant anyway):
    const float pn[8] = { pt.b, pbo.b, pm.a, pm.c, pt.a, pt.c, pbo.a, pbo.c };
    const float gn[8] = { gt_.b, gbo.b, gm.a, gm.c, gt_.a, gt_.c, gbo.a, gbo.c };

    float vp[8], vg[8], sp = 0.0f, sg = 0.0f;
    #pragma unroll
    for (int i = 0; i < 8; ++i) {
        vp[i] = pc - pn[i];
        vg[i] = gc - gn[i];
        sp += vp[i] * vp[i];
        sg += vg[i] * vg[i];
    }
    const float ip = (sp == 0.0f) ? 1.0f : rsqrtf(sp);  // ref: norm==0 -> 1
    const float ig = (sg == 0.0f) ? 1.0f : rsqrtf(sg);

    float partial = 0.0f;
    #pragma unroll
    for (int i = 0; i < 8; ++i)
        partial += fabsf(vp[i] * ip - vg[i] * ig);

    // wave-64 reduction (identical tree to the previous best version)
    #pragma unroll
    for (int o = 32; o > 0; o >>= 1)
        partial += __shfl_down(partial, o, 64);

    __shared__ float wsum[4];
    const int lane = threadIdx.x & 63;
    const int wid  = threadIdx.x >> 6;
    if (lane == 0) wsum[wid] = partial;
    __syncthreads();

    if (threadIdx.x == 0) {
        const float bsum = wsum[0] + wsum[1] + wsum[2] + wsum[3];
        // 2^31 fixed point, round-to-nearest via double (exact for fp32 in).
        const unsigned long long fx =
            (unsigned long long)__double2ll_rn((double)bsum * FX_SCALE);
        const unsigned long long mine = fx + CNT_ONE;
        const unsigned long long old = atomicAdd(&g_acc, mine);  // device scope
        const unsigned long long now = old + mine;
        if ((now >> 52) == (unsigned long long)NBLOCKS1) {
            // I'm the last arriver and `now` holds the complete sum.
            const double total = (double)(now & SUM_MASK) * (1.0 / FX_SCALE);
            out[0] = (float)(total / (double)NTERMS);
            // Reset for the next graph replay. Ordered after all adds in the
            // location's modification order; kernel-end release makes it
            // visible to the next launch.
            __hip_atomic_store(&g_acc, 0ULL,
                               __ATOMIC_RELAXED, __HIP_MEMORY_SCOPE_AGENT);
        }
    }
}

extern "C" void kernel_launch(void* const* d_in, const int* in_sizes, int n_in,
                              void* d_out, int out_size, void* d_ws, size_t ws_size,
                              hipStream_t stream) {
    const float* pred = (const float*)d_in[0];
    const float* gt   = (const float*)d_in[1];
    const int*   px   = (const int*)d_in[2];
    const int*   py   = (const int*)d_in[3];
    float* out = (float*)d_out;
    (void)d_ws; (void)ws_size;   // workspace intentionally unused

    rd_fused<<<NBLOCKS1, 256, 0, stream>>>(pred, gt, px, py, out);
}